// Round 1
// baseline (549.273 us; speedup 1.0000x reference)
//
#include <hip/hip_runtime.h>
#include <hip/hip_bf16.h>

#define LOG2E 1.44269504088896340736f

typedef __attribute__((ext_vector_type(8))) short short8;
typedef __attribute__((ext_vector_type(4))) float f32x4;

__device__ __forceinline__ short f2bf(float f) {
    unsigned u = __builtin_bit_cast(unsigned, f);
    unsigned r = (u + 0x7FFFu + ((u >> 16) & 1u)) >> 16;  // RNE
    return (short)r;
}

// ---------------- projection: q,k,v = conv1x1(feature) -------------------
// X[i][c] = feature[n][c][hw], i = n*4096 + hw  (NHWC gather)
// Qb[i][o] = dot + bq  (bf16)
// Kb[i][o] = (dot + bk) * LOG2E  (bf16; pre-scale so softmax is exp2-domain)
// VT[o][i] = dot + bv  (bf16, transposed for PV A-fragments)
__global__ __launch_bounds__(256) void proj_kernel(
    const float* __restrict__ feat,
    const float* __restrict__ Wq, const float* __restrict__ bq,
    const float* __restrict__ Wk, const float* __restrict__ bk,
    const float* __restrict__ Wv, const float* __restrict__ bv,
    short* __restrict__ Qb, short* __restrict__ Kb, short* __restrict__ VT)
{
    __shared__ __align__(16) float Xs[32 * 260];       // 32 rows x 256 c, stride 260
    __shared__ __align__(16) float Ws[3 * 128 * 20];   // [mat][o][c'], stride 20
    const int t = threadIdx.x;
    const int blk = blockIdx.x;           // 256 blocks, 32 rows each
    const int n = blk >> 7;
    const int hw0 = (blk & 127) * 32;

    // stage X tile (coalesced along rows)
    {
        const int xr = t & 31;
        const int c0 = (t >> 5) * 32;
        const float* fp = feat + (size_t)n * 256 * 4096 + hw0 + xr;
        #pragma unroll
        for (int k = 0; k < 32; ++k) {
            int c = c0 + k;
            Xs[xr * 260 + c] = fp[(size_t)c * 4096];
        }
    }

    const int r  = t >> 3;   // 0..31  row
    const int og = t & 7;    // output interleave group

    float acc[3][16];
    #pragma unroll
    for (int oi = 0; oi < 16; ++oi) {
        int o = og + 8 * oi;
        acc[0][oi] = bq[o];
        acc[1][oi] = bk[o];
        acc[2][oi] = bv[o];
    }

    for (int cc = 0; cc < 256; cc += 16) {
        __syncthreads();
        // stage W chunk (3 x 128 x 16)
        {
            int e = t;
            #pragma unroll
            for (int k = 0; k < 8; ++k) {
                int o = e >> 4, cp = e & 15;
                Ws[0 * 2560 + o * 20 + cp] = Wq[o * 256 + cc + cp];
                Ws[1 * 2560 + o * 20 + cp] = Wk[o * 256 + cc + cp];
                Ws[2 * 2560 + o * 20 + cp] = Wv[o * 256 + cc + cp];
                e += 256;
            }
        }
        __syncthreads();
        #pragma unroll
        for (int cp = 0; cp < 16; cp += 4) {
            const float4 x4 = *(const float4*)&Xs[r * 260 + cc + cp];
            #pragma unroll
            for (int mmat = 0; mmat < 3; ++mmat) {
                #pragma unroll
                for (int oi = 0; oi < 16; ++oi) {
                    const float4 w4 = *(const float4*)&Ws[mmat * 2560 + (og + 8 * oi) * 20 + cp];
                    acc[mmat][oi] += w4.x * x4.x + w4.y * x4.y + w4.z * x4.z + w4.w * x4.w;
                }
            }
        }
    }

    const int i = blk * 32 + r;
    #pragma unroll
    for (int oi = 0; oi < 16; ++oi) {
        int o = og + 8 * oi;
        Qb[i * 128 + o] = f2bf(acc[0][oi]);
        Kb[i * 128 + o] = f2bf(acc[1][oi] * LOG2E);
        VT[o * 8192 + i] = f2bf(acc[2][oi]);
    }
}

// ---------------- flash attention (1 wave = 16 rows i) -------------------
// S^T tile = mfma(A = q rows (M=j), B = k rows (N=i)): lane holds
// S^T[j = jt + 16*jh + 4*g + reg][i = ib + l15]  (g = lane>>4, l15 = lane&15)
// softmax over j (across the 4 lane-groups: shfl_xor 16,32)
// mask^T chunk = mfma(A = V^T frag, B = P^T frag)
__global__ __launch_bounds__(64) void attn_kernel(
    const short* __restrict__ Qb, const short* __restrict__ Kb,
    const short* __restrict__ VT, float* __restrict__ maskb)
{
    const int lane = threadIdx.x;
    const int l15 = lane & 15;
    const int g = lane >> 4;
    const int ib = blockIdx.x * 16;

    short8 kf[4];   // B-fragments: this wave's 16 k-rows (pre-scaled by log2e)
    {
        const short* kp = Kb + (ib + l15) * 128 + g * 8;
        #pragma unroll
        for (int dc = 0; dc < 4; ++dc) kf[dc] = *(const short8*)(kp + dc * 32);
    }

    f32x4 O[8];     // O^T acc: O[dc][reg] = maskT[16*dc + 4*g + reg][ib + l15]
    #pragma unroll
    for (int dc = 0; dc < 8; ++dc) O[dc] = (f32x4){0.f, 0.f, 0.f, 0.f};
    float m = -__builtin_inff(), s = 0.f;

    short8 qaA[2][4], vaA[8], qaB[2][4], vaB[8];

    auto load_tile = [&](int jt, short8 (&qa)[2][4], short8 (&va)[8]) {
        const short* qp = Qb + (jt + l15) * 128 + g * 8;
        #pragma unroll
        for (int dc = 0; dc < 4; ++dc) {
            qa[0][dc] = *(const short8*)(qp + dc * 32);
            qa[1][dc] = *(const short8*)(qp + 2048 + dc * 32);
        }
        const short* vp = VT + l15 * 8192 + jt + g * 8;
        #pragma unroll
        for (int dc = 0; dc < 8; ++dc)
            va[dc] = *(const short8*)(vp + dc * 131072);   // dc*16 rows of VT
    };

    auto compute_tile = [&](const short8 (&qa)[2][4], const short8 (&va)[8]) {
        f32x4 s0 = {0.f,0.f,0.f,0.f}, s1 = {0.f,0.f,0.f,0.f};
        #pragma unroll
        for (int dc = 0; dc < 4; ++dc) {
            s0 = __builtin_amdgcn_mfma_f32_16x16x32_bf16(qa[0][dc], kf[dc], s0, 0, 0, 0);
            s1 = __builtin_amdgcn_mfma_f32_16x16x32_bf16(qa[1][dc], kf[dc], s1, 0, 0, 0);
        }
        float sv[8] = {s0[0], s0[1], s0[2], s0[3], s1[0], s1[1], s1[2], s1[3]};
        float tmax = sv[0];
        #pragma unroll
        for (int e = 1; e < 8; ++e) tmax = fmaxf(tmax, sv[e]);
        tmax = fmaxf(tmax, __shfl_xor(tmax, 16));
        tmax = fmaxf(tmax, __shfl_xor(tmax, 32));
        if (!__all(tmax <= m + 8.f)) {          // defer-max (T13), exp2 domain
            float mn = fmaxf(m, tmax);
            float al = exp2f(m - mn);
            #pragma unroll
            for (int dc = 0; dc < 8; ++dc) O[dc] *= al;
            s *= al;
            m = mn;
        }
        float pv[8], psum = 0.f;
        #pragma unroll
        for (int e = 0; e < 8; ++e) { pv[e] = exp2f(sv[e] - m); psum += pv[e]; }
        psum += __shfl_xor(psum, 16);
        psum += __shfl_xor(psum, 32);
        s += psum;
        // P^T -> B-fragment: lane needs P^T[jt + 8g + e][ib + l15]
        short8 pf;
        const int srcbase = l15 + ((g & 1) << 5);
        const bool hi = (g >> 1) != 0;
        #pragma unroll
        for (int e = 0; e < 8; ++e) {
            int src = srcbase + ((e >> 2) << 4);
            float vlo = __shfl(pv[e & 3], src);
            float vhi = __shfl(pv[4 + (e & 3)], src);
            pf[e] = f2bf(hi ? vhi : vlo);
        }
        #pragma unroll
        for (int dc = 0; dc < 8; ++dc)
            O[dc] = __builtin_amdgcn_mfma_f32_16x16x32_bf16(va[dc], pf, O[dc], 0, 0, 0);
    };

    load_tile(0, qaA, vaA);
    for (int jtp = 0; jtp < 8192; jtp += 64) {
        load_tile(jtp + 32, qaB, vaB);
        compute_tile(qaA, vaA);
        if (jtp + 64 < 8192) load_tile(jtp + 64, qaA, vaA);
        compute_tile(qaB, vaB);
    }

    const float inv = 1.f / s;
    // store mask row-major: mask[i][d], d = 16*dc + 4*g + reg
    float* mp = maskb + (ib + l15) * 128 + 4 * g;
    #pragma unroll
    for (int dc = 0; dc < 8; ++dc) {
        #pragma unroll
        for (int rr = 0; rr < 4; ++rr)
            mp[dc * 16 + rr] = O[dc][rr] * inv;
    }
}

// ---------------- epilogue: out = Wm @ mask (h/w swapped) + bm + feature --
// out[n][c][x][y] = sum_ch Wm[c][ch] * mask[n*4096 + y*64 + x][ch] + bm[c]
//                   + feat[n][c][x][y]
__global__ __launch_bounds__(256) void epi_kernel(
    const float* __restrict__ maskb, const float* __restrict__ Wm,
    const float* __restrict__ bm, const float* __restrict__ feat,
    float* __restrict__ out)
{
    const int t = threadIdx.x;
    const int b = blockIdx.x;            // 256 = n(2) * x(64) * half(2)
    const int half = b & 1;
    const int x = (b >> 1) & 63;
    const int n = b >> 7;
    const int y = t & 63;
    const int cw = __builtin_amdgcn_readfirstlane(t >> 6);  // wave-uniform
    const int i = n * 4096 + y * 64 + x;

    const int cbase = half * 128 + cw * 32;
    float accv[32];
    #pragma unroll
    for (int ci = 0; ci < 32; ++ci) accv[ci] = bm[cbase + ci];

    const float4* mp = (const float4*)(maskb + (size_t)i * 128);
    for (int q = 0; q < 32; ++q) {       // runtime loop; accv stays static
        float4 mv = mp[q];
        #pragma unroll
        for (int ci = 0; ci < 32; ++ci) {
            const float4 w4 = *(const float4*)(Wm + (size_t)(cbase + ci) * 128 + q * 4);
            accv[ci] += w4.x * mv.x + w4.y * mv.y + w4.z * mv.z + w4.w * mv.w;
        }
    }
    #pragma unroll
    for (int ci = 0; ci < 32; ++ci) {
        size_t oidx = ((size_t)(n * 256 + cbase + ci) * 64 + x) * 64 + y;
        out[oidx] = accv[ci] + feat[oidx];
    }
}

extern "C" void kernel_launch(void* const* d_in, const int* in_sizes, int n_in,
                              void* d_out, int out_size, void* d_ws, size_t ws_size,
                              hipStream_t stream) {
    const float* feat = (const float*)d_in[0];
    const float* Wq = (const float*)d_in[1];
    const float* bq = (const float*)d_in[2];
    const float* Wk = (const float*)d_in[3];
    const float* bk = (const float*)d_in[4];
    const float* Wv = (const float*)d_in[5];
    const float* bv = (const float*)d_in[6];
    const float* Wm = (const float*)d_in[7];
    const float* bm = (const float*)d_in[8];
    float* out = (float*)d_out;

    short* Qb = (short*)d_ws;                     // 8192x128 bf16 (2 MB)
    short* Kb = Qb + 8192 * 128;                  // 8192x128 bf16, *log2e
    short* VT = Kb + 8192 * 128;                  // 128x8192 bf16 (transposed)
    float* maskb = (float*)(VT + 8192 * 128);     // 8192x128 f32 (4 MB)

    hipLaunchKernelGGL(proj_kernel, dim3(256), dim3(256), 0, stream,
                       feat, Wq, bq, Wk, bk, Wv, bv, Qb, Kb, VT);
    hipLaunchKernelGGL(attn_kernel, dim3(512), dim3(64), 0, stream,
                       Qb, Kb, VT, maskb);
    hipLaunchKernelGGL(epi_kernel, dim3(256), dim3(256), 0, stream,
                       maskb, Wm, bm, feat, out);
}